// Round 15
// baseline (296.885 us; speedup 1.0000x reference)
//
#include <hip/hip_runtime.h>
#include <stdint.h>

// DotAtt: B=16, Lq=Lk=2048, D=64. scores = 64*Q.K^T ; softmax over q (axis=-2);
// JAX threefry dropout p=0.1 (key 42, partitionable, bits=x0^x1); out = W.V
// Pass 0: pre-split Q,K -> bf16 hi/lo in ws; zero Out.
// Pass 1: partial column stats; wave holds B-frags for 64 cols, scans 128-row
//         q-slice, 8 independent 3-MFMA chains per 4 A-loads. 4 q-quarters.
// Pass 1b: merge 4 partials -> Mcol, Rcol.
// Pass 2: O += (exp(s-M)*R*keep) . V per k-half, atomicAdd into zeroed Out.
// score_split used by BOTH passes -> s bitwise identical (M consistency).

#define LQ 2048
#define DD 64
#define NQ (16 * LQ * DD)   // 2,097,152 elems per tensor

typedef short bf16x8 __attribute__((ext_vector_type(8)));
typedef float f32x4 __attribute__((ext_vector_type(4)));
typedef unsigned short ushort_t;

#define MFMA16(a, b, c) __builtin_amdgcn_mfma_f32_16x16x32_bf16(a, b, c, 0, 0, 0)

__device__ __forceinline__ ushort_t f2bf(float x) {
  uint32_t u = __float_as_uint(x);
  return (ushort_t)((u + 0x7FFFu + ((u >> 16) & 1u)) >> 16);  // RNE
}
__device__ __forceinline__ float bf2f(ushort_t h) {
  return __uint_as_float(((uint32_t)h) << 16);
}

// 16x16 score tile, two INDEPENDENT 3-MFMA chains (d-halves), summed at end.
// Identical sequence in both passes -> bit-identical s.
__device__ __forceinline__ f32x4 score_split(bf16x8 Ah0, bf16x8 Ah1, bf16x8 Al0, bf16x8 Al1,
                                             bf16x8 Bh0, bf16x8 Bh1, bf16x8 Bl0, bf16x8 Bl1) {
  f32x4 a0 = {0.f, 0.f, 0.f, 0.f};
  f32x4 a1 = {0.f, 0.f, 0.f, 0.f};
  a0 = MFMA16(Ah0, Bh0, a0);
  a0 = MFMA16(Al0, Bh0, a0);
  a0 = MFMA16(Ah0, Bl0, a0);
  a1 = MFMA16(Ah1, Bh1, a1);
  a1 = MFMA16(Al1, Bh1, a1);
  a1 = MFMA16(Ah1, Bl1, a1);
  return a0 + a1;
}

__device__ __forceinline__ void tf_round(uint32_t& x0, uint32_t& x1, const int r) {
  x0 += x1;
  x1 = (x1 << r) | (x1 >> (32 - r));
  x1 ^= x0;
}

// JAX threefry2x32 partitionable draw: bits = x0^x1, key=(0,42), ctr=(0,j). Verified r9.
__device__ __forceinline__ bool keep_bit(uint32_t j) {
  const uint32_t ks1 = 42u, ks2 = 0x1BD11BDAu ^ 42u;
  uint32_t x0 = 0u;
  uint32_t x1 = j + ks1;
  tf_round(x0,x1,13); tf_round(x0,x1,15); tf_round(x0,x1,26); tf_round(x0,x1,6);
  x0 += ks1; x1 += ks2 + 1u;
  tf_round(x0,x1,17); tf_round(x0,x1,29); tf_round(x0,x1,16); tf_round(x0,x1,24);
  x0 += ks2; x1 += 0u + 2u;
  tf_round(x0,x1,13); tf_round(x0,x1,15); tf_round(x0,x1,26); tf_round(x0,x1,6);
  x0 += 0u; x1 += ks1 + 3u;
  tf_round(x0,x1,17); tf_round(x0,x1,29); tf_round(x0,x1,16); tf_round(x0,x1,24);
  x0 += ks1; x1 += ks2 + 4u;
  tf_round(x0,x1,13); tf_round(x0,x1,15); tf_round(x0,x1,26); tf_round(x0,x1,6);
  x0 += ks2; x1 += 0u + 5u;
  uint32_t bits = x0 ^ x1;
  float u = __uint_as_float((bits >> 9) | 0x3F800000u) - 1.0f;
  return u < 0.9f;
}

// ---------------- Pass 0: pre-split Q,K -> bf16 hi/lo; zero Out -------------
__global__ __launch_bounds__(256) void split_qk(
    const float* __restrict__ Q, const float* __restrict__ K,
    ushort_t* __restrict__ Qh, ushort_t* __restrict__ Ql,
    ushort_t* __restrict__ Kh, ushort_t* __restrict__ Kl,
    float* __restrict__ Out) {
  const int total4 = (2 * NQ) / 4;          // 1,048,576 float4 groups
  const int stride = 1024 * 256;
  const int base = blockIdx.x * 256 + threadIdx.x;
  for (int i = base; i < total4; i += stride) {
    const bool isK = i >= NQ / 4;           // wave-uniform (NQ/4 % 64 == 0)
    const int j = isK ? i - NQ / 4 : i;
    float4 v = ((const float4*)(isK ? K : Q))[j];
    short4 h, l;
    ushort_t t;
    t = f2bf(v.x); h.x = (short)t; l.x = (short)f2bf(v.x - bf2f(t));
    t = f2bf(v.y); h.y = (short)t; l.y = (short)f2bf(v.y - bf2f(t));
    t = f2bf(v.z); h.z = (short)t; l.z = (short)f2bf(v.z - bf2f(t));
    t = f2bf(v.w); h.w = (short)t; l.w = (short)f2bf(v.w - bf2f(t));
    *(short4*)&(isK ? Kh : Qh)[(size_t)j * 4] = h;
    *(short4*)&(isK ? Kl : Ql)[(size_t)j * 4] = l;
  }
  const float4 z4 = {0.f, 0.f, 0.f, 0.f};
  for (int i = base; i < NQ / 4; i += stride) ((float4*)Out)[i] = z4;
}

// ---------------- Pass 1: partial column stats ------------------------------
// 2048 blocks = b(16) x ktile(32) x qquarter(4); 256 thr. Each wave: B-frags
// for ALL 64 cols in regs, scans its private 128-row q-slice. One barrier.
__global__ __launch_bounds__(256, 4) void dotatt_colstats(
    const ushort_t* __restrict__ Qh, const ushort_t* __restrict__ Ql,
    const ushort_t* __restrict__ Kh, const ushort_t* __restrict__ Kl,
    float2* __restrict__ MZpart) {
  __shared__ float2 mzbuf[4][4][16];   // [wave][cgroup][kr]

  const int bid = blockIdx.x;
  const int b = bid >> 7;
  const int ktile = (bid >> 2) & 31;
  const int qs = bid & 3;
  const int tid = threadIdx.x;
  const int lane = tid & 63;
  const int g = tid >> 6;
  const int kr = lane & 15;
  const int d0 = (lane >> 4) << 3;

  const size_t qb = (size_t)b * LQ * DD;

  // B frags for all 64 k-cols (4 groups of 16): 64 VGPR
  bf16x8 Bh0[4], Bh1[4], Bl0[4], Bl1[4];
#pragma unroll
  for (int c = 0; c < 4; ++c) {
    const size_t krow = qb + (size_t)((ktile << 6) + (c << 4) + kr) * DD;
    Bh0[c] = *(const bf16x8*)&Kh[krow + d0];
    Bh1[c] = *(const bf16x8*)&Kh[krow + d0 + 32];
    Bl0[c] = *(const bf16x8*)&Kl[krow + d0];
    Bl1[c] = *(const bf16x8*)&Kl[krow + d0 + 32];
  }

  float m[4], z[4];
#pragma unroll
  for (int c = 0; c < 4; ++c) { m[c] = -1e30f; z[c] = 0.f; }

  const int row0 = (qs << 9) + (g << 7);   // qs*512 + wave*128

#pragma unroll 1
  for (int it = 0; it < 8; ++it) {
    const size_t qrow = qb + (size_t)(row0 + (it << 4) + kr) * DD;
    bf16x8 Ah0 = *(const bf16x8*)&Qh[qrow + d0];
    bf16x8 Ah1 = *(const bf16x8*)&Qh[qrow + d0 + 32];
    bf16x8 Al0 = *(const bf16x8*)&Ql[qrow + d0];
    bf16x8 Al1 = *(const bf16x8*)&Ql[qrow + d0 + 32];
#pragma unroll
    for (int c = 0; c < 4; ++c) {
      f32x4 s = score_split(Ah0, Ah1, Al0, Al1, Bh0[c], Bh1[c], Bl0[c], Bl1[c]);
      float s0 = s[0] * 64.f, s1 = s[1] * 64.f, s2 = s[2] * 64.f, s3 = s[3] * 64.f;
      float mx = fmaxf(fmaxf(s0, s1), fmaxf(s2, s3));
      if (!__all(mx < m[c] - 20.f)) {
        float mn = fmaxf(m[c], mx);
        z[c] = z[c] * __expf(m[c] - mn) + __expf(s0 - mn) + __expf(s1 - mn)
             + __expf(s2 - mn) + __expf(s3 - mn);
        m[c] = mn;
      }
    }
  }
  // merge hi-groups (disjoint q rows, same col)
#pragma unroll
  for (int c = 0; c < 4; ++c) {
#pragma unroll
    for (int off = 16; off < 64; off <<= 1) {
      float om = __shfl_xor(m[c], off);
      float oz = __shfl_xor(z[c], off);
      float mn = fmaxf(m[c], om);
      z[c] = z[c] * __expf(m[c] - mn) + oz * __expf(om - mn);
      m[c] = mn;
    }
  }
  if (lane < 16) {
#pragma unroll
    for (int c = 0; c < 4; ++c) mzbuf[g][c][lane] = make_float2(m[c], z[c]);
  }
  __syncthreads();
  // merge the 4 waves' disjoint q-slices (fixed order g=0..3)
  if (tid < 64) {
    const int c = tid >> 4, k = tid & 15;
    float2 p = mzbuf[0][c][k];
    float M = p.x, Z = p.y;
#pragma unroll
    for (int gg = 1; gg < 4; ++gg) {
      float2 q = mzbuf[gg][c][k];
      float mn = fmaxf(M, q.x);
      Z = Z * __expf(M - mn) + q.y * __expf(q.x - mn);
      M = mn;
    }
    MZpart[((size_t)qs * 16 + b) * LQ + (ktile << 6) + (c << 4) + k] = make_float2(M, Z);
  }
}

// ---------------- Pass 1b: merge 4 q-quarter partials -> Mcol, Rcol ---------
__global__ __launch_bounds__(256) void merge_stats(
    const float2* __restrict__ MZpart,
    float* __restrict__ Mcol, float* __restrict__ Rcol) {
  const int i = blockIdx.x * 256 + threadIdx.x;   // (b,col): 32768 total
  float2 p0 = MZpart[i];
  float2 p1 = MZpart[32768 + i];
  float2 p2 = MZpart[65536 + i];
  float2 p3 = MZpart[98304 + i];
  float M = fmaxf(fmaxf(p0.x, p1.x), fmaxf(p2.x, p3.x));
  float Z = p0.y * __expf(p0.x - M) + p1.y * __expf(p1.x - M)
          + p2.y * __expf(p2.x - M) + p3.y * __expf(p3.x - M);
  Mcol[i] = M;
  Rcol[i] = 1.0f / (0.9f * Z);
}

// ---------------- Pass 2: O += (exp(s-M)*R*keep) . V per k-half -------------
// 1024 blocks = b(16) x qtile(32) x khalf(2); 256 thr. Wave g owns 256 k
// (16 iters). Q frags fragment-major LDS; Slds bounce; atomicAdd epilogue.
__global__ __launch_bounds__(256, 4) void dotatt_out(
    const float* __restrict__ V,
    const ushort_t* __restrict__ Qh, const ushort_t* __restrict__ Ql,
    const ushort_t* __restrict__ Kh, const ushort_t* __restrict__ Kl,
    const float* __restrict__ Mcol, const float* __restrict__ Rcol,
    float* __restrict__ Out) {
  __shared__ ushort_t qf[4][4][64][8];   // [qtile][frag][lane][8] = 16KB
  __shared__ float Slds[4][64][17];      // wave-private S tiles; epilogue reuse

  const int bid = blockIdx.x;
  const int b = bid >> 6;
  const int qbase = ((bid >> 1) & 31) << 6;
  const int khalf = bid & 1;
  const int tid = threadIdx.x;
  const int lane = tid & 63;
  const int g = tid >> 6;
  const int kr = lane & 15;
  const int hi = lane >> 4;
  const int d0 = hi << 3;

  const size_t qb = (size_t)b * LQ * DD;
  // stage Q frags once: 1024 16B slots, 4/thread
#pragma unroll
  for (int i = 0; i < 4; ++i) {
    int s = tid + (i << 8);
    int qt = (s >> 8) & 3, f = (s >> 6) & 3, ln = s & 63;
    int srow = qbase + (qt << 4) + (ln & 15);
    int scol = ((ln >> 4) << 3) + ((f & 1) << 5);
    const ushort_t* src = (f < 2) ? Qh : Ql;
    *(bf16x8*)&qf[qt][f][ln][0] =
        *(const bf16x8*)&src[qb + (size_t)srow * DD + scol];
  }
  __syncthreads();

  float acc[64];
#pragma unroll
  for (int d = 0; d < 64; ++d) acc[d] = 0.f;

  const float* Vb = V + qb;
  const float* Mb = Mcol + (size_t)b * LQ;
  const float* Rb = Rcol + (size_t)b * LQ;
  const uint32_t jrow = ((uint32_t)b * LQ + (uint32_t)(qbase + lane)) * (uint32_t)LQ;

#pragma unroll 1
  for (int t = 0; t < 16; ++t) {
    const int k0 = (khalf << 10) + (g << 8) + (t << 4);
    const size_t krow = qb + (size_t)(k0 + kr) * DD;
    bf16x8 Bh0 = *(const bf16x8*)&Kh[krow + d0];
    bf16x8 Bh1 = *(const bf16x8*)&Kh[krow + d0 + 32];
    bf16x8 Bl0 = *(const bf16x8*)&Kl[krow + d0];
    bf16x8 Bl1 = *(const bf16x8*)&Kl[krow + d0 + 32];
    const float Mw = Mb[k0 + kr];
    const float rr = Rb[k0 + kr];

    float sm[16];
#pragma unroll
    for (int qt = 0; qt < 4; ++qt) {
      bf16x8 Ah0 = *(const bf16x8*)&qf[qt][0][lane][0];
      bf16x8 Ah1 = *(const bf16x8*)&qf[qt][1][lane][0];
      bf16x8 Al0 = *(const bf16x8*)&qf[qt][2][lane][0];
      bf16x8 Al1 = *(const bf16x8*)&qf[qt][3][lane][0];
      f32x4 s = score_split(Ah0, Ah1, Al0, Al1, Bh0, Bh1, Bl0, Bl1);
#pragma unroll
      for (int r = 0; r < 4; ++r) sm[(qt << 2) + r] = s[r] * 64.f - Mw;
    }
    float mx = sm[0];
#pragma unroll
    for (int i = 1; i < 16; ++i) mx = fmaxf(mx, sm[i]);
    if (__all(mx < -25.f)) continue;          // whole 64q x 16k chunk negligible

    // bounce S to wave-private LDS (lane holds col kr, rows qt*16+hi*4+r)
#pragma unroll
    for (int qt = 0; qt < 4; ++qt)
#pragma unroll
      for (int r = 0; r < 4; ++r)
        Slds[g][(qt << 4) + (hi << 2) + r][kr] = sm[(qt << 2) + r];

#pragma unroll 1
    for (int kk = 0; kk < 16; ++kk) {
      float smv = Slds[g][lane][kk];          // lane = q row
      if (__all(smv < -25.f)) continue;
      float Rk = __shfl(rr, kk);
      float w = __expf(smv) * Rk;
      if (!keep_bit(jrow + (uint32_t)(k0 + kk))) w = 0.f;
      const float4* vrow = (const float4*)(Vb + (size_t)(k0 + kk) * DD);  // uniform broadcast
#pragma unroll
      for (int c4 = 0; c4 < 16; ++c4) {
        float4 vv = vrow[c4];
        acc[4 * c4 + 0] += w * vv.x;
        acc[4 * c4 + 1] += w * vv.y;
        acc[4 * c4 + 2] += w * vv.z;
        acc[4 * c4 + 3] += w * vv.w;
      }
    }
  }

  __syncthreads();
  // reduce 4 wave-partials (reuse Slds region: 64*68 = 4352 f32 = 4*64*17)
  float (*qs)[68] = (float(*)[68])&Slds[0][0][0];
  for (int gg = 0; gg < 4; ++gg) {
    if (g == gg) {
      if (gg == 0) {
#pragma unroll
        for (int d = 0; d < 64; ++d) qs[lane][d] = acc[d];
      } else {
#pragma unroll
        for (int d = 0; d < 64; ++d) qs[lane][d] += acc[d];
      }
    }
    __syncthreads();
  }

  float* Ob = Out + ((size_t)b * LQ + qbase) * DD;
#pragma unroll
  for (int i = 0; i < 16; ++i) {
    int idx = tid + (i << 8);          // 0..4095
    int r = idx >> 6, c = idx & 63;
    atomicAdd(&Ob[(size_t)r * DD + c], qs[r][c]);
  }
}

extern "C" void kernel_launch(void* const* d_in, const int* in_sizes, int n_in,
                              void* d_out, int out_size, void* d_ws, size_t ws_size,
                              hipStream_t stream) {
  const float* Q = (const float*)d_in[0];
  const float* K = (const float*)d_in[1];
  const float* V = (const float*)d_in[2];
  float* Out = (float*)d_out;

  ushort_t* Qh = (ushort_t*)d_ws;           // 4MB each
  ushort_t* Ql = Qh + NQ;
  ushort_t* Kh = Ql + NQ;
  ushort_t* Kl = Kh + NQ;
  float2* MZpart = (float2*)(Kl + NQ);      // 4*32768 float2 = 1MB
  float* Mcol = (float*)(MZpart + 4 * 32768);  // 128KB
  float* Rcol = Mcol + (size_t)16 * LQ;        // 128KB (~17.5MB total)

  hipLaunchKernelGGL(split_qk, dim3(1024), dim3(256), 0, stream,
                     Q, K, Qh, Ql, Kh, Kl, Out);
  hipLaunchKernelGGL(dotatt_colstats, dim3(16 * 32 * 4), dim3(256), 0, stream,
                     Qh, Ql, Kh, Kl, MZpart);
  hipLaunchKernelGGL(merge_stats, dim3(128), dim3(256), 0, stream,
                     MZpart, Mcol, Rcol);
  hipLaunchKernelGGL(dotatt_out, dim3(16 * 32 * 2), dim3(256), 0, stream,
                     V, Qh, Ql, Kh, Kl, Mcol, Rcol, Out);
}